// Round 10
// baseline (337.722 us; speedup 1.0000x reference)
//
#include <hip/hip_runtime.h>
#include <math.h>

#define NN 4096
#define DD 512
#define INV_TAU 5.0f
#define EPSV 1e-15f

typedef unsigned short u16;
typedef unsigned long long u64;
typedef __attribute__((ext_vector_type(8))) short short8;
typedef __attribute__((ext_vector_type(4))) float f32x4;

__device__ __forceinline__ void gld16(const void* g, void* l) {
  __builtin_amdgcn_global_load_lds(
      (const __attribute__((address_space(1))) unsigned int*)g,
      (__attribute__((address_space(3))) unsigned int*)l, 16, 0, 0);
}

__device__ __forceinline__ void bar_vm4() {
  asm volatile("s_waitcnt vmcnt(4) lgkmcnt(0)\n\ts_barrier" ::: "memory");
}
__device__ __forceinline__ void bar_vm0() {
  asm volatile("s_waitcnt vmcnt(0) lgkmcnt(0)\n\ts_barrier" ::: "memory");
}

__device__ __forceinline__ float bf2f(u16 u) {
  return __uint_as_float(((unsigned)u) << 16);
}
__device__ __forceinline__ u16 f2bf(float x) {  // RNE
  unsigned u = __float_as_uint(x);
  u += 0x7fff + ((u >> 16) & 1);
  return (u16)(u >> 16);
}

__device__ __forceinline__ float wave_sum(float v) {
#pragma unroll
  for (int o = 32; o > 0; o >>= 1) v += __shfl_down(v, o, 64);
  return v;
}

// ------- node 1: weights fp32->bf16 (lw1|lw2) + zero zbf ---------------------
__global__ __launch_bounds__(256) void tobf16w(const float* __restrict__ a,
                                               const float* __restrict__ b,
                                               u16* __restrict__ o,
                                               float* __restrict__ zbf) {
  const int bid = blockIdx.x, tid = threadIdx.x;
  if (bid < 128) zbf[bid * 256 + tid] = 0.f;
  const int i = bid * 256 + tid;  // < 131072 float4s
  const float* s = (i < 65536) ? a + (size_t)i * 4 : b + (size_t)(i - 65536) * 4;
  float4 v = *(const float4*)s;
  u64 pk = (u64)f2bf(v.x) | ((u64)f2bf(v.y) << 16) | ((u64)f2bf(v.z) << 32) |
           ((u64)f2bf(v.w) << 48);
  *(u64*)&o[(size_t)i * 4] = pk;
}

// ------- node 2: FUSED HEAD: z -> bf16 -> gemm1(PReLU) -> gemm2 -> L2norm ----
// 256 blocks (1/CU) x 512 thr; block = 32-row band of one batch.
// LDS 96 KiB: Atile 32K (16 chunks x [2 grp x 512 u16], proven slot layout) |
// Wb0 32K | Wb1 32K. W staged per-kc (proven stage pattern), depth-2 drain.
// Side effect: colmean partials pc[band][512] (free — z already in regs).
__global__ __launch_bounds__(512) void head_fused(
    const float* __restrict__ z1, const float* __restrict__ z2,
    const u16* __restrict__ W1b, const u16* __restrict__ W2b,
    const float* __restrict__ lb1, const float* __restrict__ la,
    const float* __restrict__ lb2, u16* __restrict__ NAb,
    float* __restrict__ pc1, float* __restrict__ pc2) {
  extern __shared__ __align__(16) u16 shm[];  // 98304 B
  u16* Atile = shm;                            // 16384 u16
  u16* Wb0 = shm + 16384;
  u16* Wb1 = shm + 32768;
  const int tid = threadIdx.x, w = tid >> 6, lane = tid & 63;
  const int quad = lane >> 4, m16 = lane & 15;
  const int bid = blockIdx.x;
  const int bz = bid >> 7, band = bid & 127;
  const int i0 = band * 32;
  const float* zsrc = bz ? z2 : z1;
  u16* ob = NAb + (size_t)bz * ((size_t)NN * DD);
  float* pcd = bz ? pc2 : pc1;
  const int roff =
      (m16 >> 1) * 64 + (((((m16 & 1) << 2) | quad) ^ (m16 >> 1)) * 8);
  const int st = (lane & 7) ^ (lane >> 3);
  const int srow = 2 * (lane >> 3) + (st >> 2);
  const int scol = (st & 3) * 8;
  // wave stages W rows w*64..w*64+63 of k-chunk k (proven pattern)
  auto stageW = [&](const u16* Wsrc, int k, u16* dst) {
    const int kn = k * 32;
#pragma unroll
    for (int rr = 0; rr < 64; rr += 16)
      gld16(&Wsrc[(size_t)(w * 64 + rr + srow) * DD + kn + scol],
            dst + (w * 64 + rr) * 32);
  };
  stageW(W1b, 0, Wb0);
  // ---- convert: z band -> Atile (slot layout) + colmean partials ----
  float* pcs = (float*)(shm + 32768);  // 4x512 f32 scratch in Wb1 (pre-kc1)
  {
    const int sub = tid >> 7;          // 0..3
    const int c0 = (tid & 127) * 4;    // col base
    const int c = c0 >> 5, cc = c0 & 31;
    const int eg = (cc >> 3) & 3, inner = cc & 7;
    float p0 = 0.f, p1 = 0.f, p2 = 0.f, p3 = 0.f;
#pragma unroll
    for (int rr = 0; rr < 8; ++rr) {
      const int row = rr * 4 + sub;
      float4 v = *(const float4*)&zsrc[(size_t)(i0 + row) * DD + c0];
      p0 += v.x; p1 += v.y; p2 += v.z; p3 += v.w;
      u64 pk = (u64)f2bf(v.x) | ((u64)f2bf(v.y) << 16) |
               ((u64)f2bf(v.z) << 32) | ((u64)f2bf(v.w) << 48);
      const int g = row >> 4, r15 = row & 15, p = r15 >> 1, rl = r15 & 1;
      const int l = p * 8 + ((rl * 4 + eg) ^ p);
      *(u64*)&Atile[c * 1024 + g * 512 + l * 8 + inner] = pk;
    }
    *(float4*)&pcs[sub * 512 + c0] = make_float4(p0, p1, p2, p3);
  }
  __syncthreads();
  {  // pc reduce: col = tid
    float s4 = pcs[tid] + pcs[512 + tid] + pcs[1024 + tid] + pcs[1536 + tid];
    pcd[band * 512 + tid] = s4;
  }
  bar_vm0();  // drain W1-kc0; pcs region free
  // ---- gemm1 K-loop (depth-2 drain, r8-proven shape) ----
  f32x4 acc[2][4] = {};
  for (int kc = 0; kc < 16; ++kc) {
    if (kc < 15) stageW(W1b, kc + 1, (kc & 1) ? Wb0 : Wb1);
    const u16* Wc = (kc & 1) ? Wb1 : Wb0;
    short8 ar[2], br[4];
    ar[0] = *(const short8*)&Atile[kc * 1024 + roff];
    ar[1] = *(const short8*)&Atile[kc * 1024 + 512 + roff];
#pragma unroll
    for (int sj = 0; sj < 4; ++sj)
      br[sj] = *(const short8*)&Wc[(w * 64 + sj * 16) * 32 + roff];
    __builtin_amdgcn_s_setprio(1);
#pragma unroll
    for (int si = 0; si < 2; ++si)
#pragma unroll
      for (int sj = 0; sj < 4; ++sj)
        acc[si][sj] = __builtin_amdgcn_mfma_f32_16x16x32_bf16(
            ar[si], br[sj], acc[si][sj], 0, 0, 0);
    __builtin_amdgcn_s_setprio(0);
    if (kc < 15) bar_vm0();
  }
  __syncthreads();
  stageW(W2b, 0, Wb0);  // overlap W2-kc0 with epilogue1
  // ---- epilogue1: prelu(acc+lb1) -> bf16 -> Atile (same slot layout) ----
  {
    const float al = la[0];
#pragma unroll
    for (int si = 0; si < 2; ++si)
#pragma unroll
      for (int sj = 0; sj < 4; ++sj) {
        const int col = w * 64 + sj * 16 + m16;
        const float bv = lb1[col];
        const int c = col >> 5, cc = col & 31;
        const int eg = (cc >> 3) & 3, inner = cc & 7;
#pragma unroll
        for (int r = 0; r < 4; ++r) {
          const int r15 = quad * 4 + r;
          const int p = r15 >> 1, rl = r15 & 1;
          const int l = p * 8 + ((rl * 4 + eg) ^ p);
          float x = acc[si][sj][r] + bv;
          x = (x >= 0.f) ? x : al * x;
          Atile[c * 1024 + si * 512 + l * 8 + inner] = f2bf(x);
        }
      }
  }
  bar_vm0();  // out1 visible + W2-kc0 drained
  // ---- gemm2 K-loop ----
  f32x4 a2[2][4] = {};
  for (int kc = 0; kc < 16; ++kc) {
    if (kc < 15) stageW(W2b, kc + 1, (kc & 1) ? Wb0 : Wb1);
    const u16* Wc = (kc & 1) ? Wb1 : Wb0;
    short8 ar[2], br[4];
    ar[0] = *(const short8*)&Atile[kc * 1024 + roff];
    ar[1] = *(const short8*)&Atile[kc * 1024 + 512 + roff];
#pragma unroll
    for (int sj = 0; sj < 4; ++sj)
      br[sj] = *(const short8*)&Wc[(w * 64 + sj * 16) * 32 + roff];
    __builtin_amdgcn_s_setprio(1);
#pragma unroll
    for (int si = 0; si < 2; ++si)
#pragma unroll
      for (int sj = 0; sj < 4; ++sj)
        a2[si][sj] = __builtin_amdgcn_mfma_f32_16x16x32_bf16(
            ar[si], br[sj], a2[si][sj], 0, 0, 0);
    __builtin_amdgcn_s_setprio(0);
    if (kc < 15) bar_vm0();
  }
  __syncthreads();
  // ---- epilogue2: +lb2 -> bf16 roundtrip -> row L2-norm -> na/nb ----
  float* ns = (float*)(shm + 16384);  // [32][8] partials + inv[32]
  float fl[2][4][4];
  float ssr[2][4] = {};
#pragma unroll
  for (int si = 0; si < 2; ++si)
#pragma unroll
    for (int sj = 0; sj < 4; ++sj) {
      const float bv = lb2[w * 64 + sj * 16 + m16];
#pragma unroll
      for (int r = 0; r < 4; ++r) {
        const float f = bf2f(f2bf(a2[si][sj][r] + bv));
        fl[si][sj][r] = f;
        ssr[si][r] = fmaf(f, f, ssr[si][r]);
      }
    }
#pragma unroll
  for (int si = 0; si < 2; ++si)
#pragma unroll
    for (int r = 0; r < 4; ++r) {
      float v = ssr[si][r];
      v += __shfl_xor(v, 1, 64);
      v += __shfl_xor(v, 2, 64);
      v += __shfl_xor(v, 4, 64);
      v += __shfl_xor(v, 8, 64);
      if (m16 == 0) ns[(si * 16 + quad * 4 + r) * 8 + w] = v;
    }
  __syncthreads();
  if (tid < 32) {
    float s = 0.f;
#pragma unroll
    for (int q = 0; q < 8; ++q) s += ns[tid * 8 + q];
    ns[256 + tid] = 1.f / fmaxf(sqrtf(s), 1e-12f);
  }
  __syncthreads();
#pragma unroll
  for (int si = 0; si < 2; ++si)
#pragma unroll
    for (int r = 0; r < 4; ++r) {
      const int row = si * 16 + quad * 4 + r;
      const float inv = ns[256 + row];
#pragma unroll
      for (int sj = 0; sj < 4; ++sj) {
        const int col = w * 64 + sj * 16 + m16;
        ob[(size_t)(i0 + row) * DD + col] = f2bf(fl[si][sj][r] * inv);
      }
    }
}

// ------- node 3: mvh — pc -> sv -> t (redundant per block) -> hg slice -------
// 128 blocks x 256 thr (64 per batch). Block writes hg rows [sub*8, sub*8+8).
__global__ __launch_bounds__(256) void mvh(
    const float* __restrict__ pc1, const float* __restrict__ pc2,
    const float* __restrict__ gw1, const float* __restrict__ gb1,
    const float* __restrict__ ga, const float* __restrict__ gw2,
    const float* __restrict__ gb2, float* __restrict__ hg) {
  __shared__ float svb[512], tvb[512];
  const int bid = blockIdx.x, tid = threadIdx.x;
  const int bz = bid >> 6, sub = bid & 63;
  const float* pc = bz ? pc2 : pc1;
  const int lane = tid & 63, w = tid >> 6;  // 4 waves
  {
    float a0 = 0.f, a1 = 0.f;
    for (int b = 0; b < 128; ++b) {
      a0 += pc[b * 512 + tid];
      a1 += pc[b * 512 + 256 + tid];
    }
    svb[tid] = a0 * (1.f / NN);
    svb[256 + tid] = a1 * (1.f / NN);
  }
  __syncthreads();
  const float al = ga[0];
  for (int rr = 0; rr < 128; ++rr) {  // wave w owns rows w*128..+127
    const int row = w * 128 + rr;
    float acc = 0.f;
#pragma unroll
    for (int q = 0; q < 8; ++q)
      acc = fmaf(gw1[(size_t)row * DD + lane + 64 * q], svb[lane + 64 * q],
                 acc);
    acc = wave_sum(acc);
    if (lane == 0) {
      acc += gb1[row];
      tvb[row] = (acc >= 0.f) ? acc : al * acc;
    }
  }
  __syncthreads();
#pragma unroll
  for (int rr = 0; rr < 2; ++rr) {  // hg slice: 8 rows, 2 per wave
    const int row = sub * 8 + w * 2 + rr;
    float acc = 0.f;
#pragma unroll
    for (int q = 0; q < 8; ++q)
      acc = fmaf(gw2[(size_t)row * DD + lane + 64 * q], tvb[lane + 64 * q],
                 acc);
    acc = wave_sum(acc);
    if (lane == 0) hg[bz * 512 + row] = acc + gb2[row];
  }
}

// ------- node 4: fused similarity (EXACT r5 body) + logsig blocks that now
// compute summ = W @ hg in-block (race-free). grid (32, 34). -----------------
__global__ __launch_bounds__(512) void sim_mfma(
    const u16* __restrict__ na, const u16* __restrict__ nb,
    const int* __restrict__ mask, float* __restrict__ zb,
    const float* __restrict__ z1g, const float* __restrict__ z2g,
    const float* __restrict__ Wd, const float* __restrict__ hg,
    float* __restrict__ plsP, float* __restrict__ plsN) {
  extern __shared__ __align__(16) u16 shm[];  // 96 KiB dynamic
  const int tid = threadIdx.x;
  const int w = tid >> 6, lane = tid & 63;
  if (blockIdx.y < 2) {  // ---- logsig partials: 64 blocks ----
    const int lx = blockIdx.y * 32 + blockIdx.x;
    const int bz = lx >> 5, bx5 = lx & 31;
    float* smP = (float*)shm;   // own batch summ
    float* smN = smP + 512;     // other batch summ
    float* red = smN + 512;
#pragma unroll
    for (int q = 0; q < 2; ++q) {
      const float* hgq = hg + q * 512;
      float* dst = (q == bz) ? smP : smN;
      for (int rr = 0; rr < 64; ++rr) {
        const int row = w * 64 + rr;
        float acc = 0.f;
#pragma unroll
        for (int t = 0; t < 8; ++t)
          acc = fmaf(Wd[(size_t)row * DD + lane + 64 * t], hgq[lane + 64 * t],
                     acc);
        acc = wave_sum(acc);
        if (lane == 0) dst[row] = acc;
      }
    }
    __syncthreads();
    const float* z = bz ? z2g : z1g;
    float lp = 0.f, ln_ = 0.f;
    for (int k = 0; k < 16; ++k) {
      const int row = bx5 * 128 + w * 16 + k;
      float dp = 0.f, dn = 0.f;
#pragma unroll
      for (int t = 0; t < 8; ++t) {
        const float zv = z[(size_t)row * DD + lane + 64 * t];
        dp = fmaf(zv, smP[lane + 64 * t], dp);
        dn = fmaf(zv, smN[lane + 64 * t], dn);
      }
      dp = wave_sum(dp);
      dn = wave_sum(dn);
      if (lane == 0) {
        lp += -logf(1.f / (1.f + __expf(-dp)) + EPSV);
        ln_ += -logf(1.f - 1.f / (1.f + __expf(-dn)) + EPSV);
      }
    }
    if (lane == 0) { red[w] = lp; red[8 + w] = ln_; }
    __syncthreads();
    if (tid == 0) {
      float sP = 0.f, sN = 0.f;
      for (int q = 0; q < 8; ++q) { sP += red[q]; sN += red[8 + q]; }
      plsP[lx] = sP;
      plsN[lx] = sN;
    }
    return;
  }
  const int quad = lane >> 4, m16 = lane & 15;
  const int ig = w & 3, jh = w >> 2;
  const int i0 = (blockIdx.y - 2) * 128, j0 = blockIdx.x * 128;
  const int roff =
      (m16 >> 1) * 64 + (((((m16 & 1) << 2) | quad) ^ (m16 >> 1)) * 8);
  const int st = (lane & 7) ^ (lane >> 3);
  const int srow = 2 * (lane >> 3) + (st >> 2);
  const int scol = (st & 3) * 8;
  const int p = w >> 1, rh = (w & 1) * 64;
  const u16* gs = (p & 1) ? nb : na;
  const int gr = ((p < 2) ? i0 : j0) + rh + srow;
  u16* dst0 = shm + p * 4096 + rh * 32;
  auto stage = [&](int bo, int k) {
    const int kn = k * 32;
#pragma unroll
    for (int rr = 0; rr < 64; rr += 16)
      gld16(&gs[(size_t)(gr + rr) * DD + kn + scol], dst0 + bo + rr * 32);
  };
  stage(0, 0);
  stage(16384, 1);
  bar_vm4();
  f32x4 a11[2][4] = {}, a12[2][4] = {}, a22[2][4] = {};
  int ro = 0;
  for (int kc = 0; kc < 16; ++kc) {
    if (kc <= 13) {
      int so = ro + 32768;
      if (so >= 49152) so -= 49152;
      stage(so, kc + 2);
    }
    const u16* Ai = shm + ro;
    const u16* Bi = shm + ro + 4096;
    const u16* Aj = shm + ro + 8192;
    const u16* Bj = shm + ro + 12288;
    short8 ai0 = *(const short8*)&Ai[(ig * 32) * 32 + roff];
    short8 ai1 = *(const short8*)&Ai[(ig * 32 + 16) * 32 + roff];
    short8 bi0 = *(const short8*)&Bi[(ig * 32) * 32 + roff];
    short8 bi1 = *(const short8*)&Bi[(ig * 32 + 16) * 32 + roff];
#pragma unroll
    for (int c = 0; c < 4; ++c) {
      short8 aj = *(const short8*)&Aj[(jh * 64 + c * 16) * 32 + roff];
      short8 bj = *(const short8*)&Bj[(jh * 64 + c * 16) * 32 + roff];
      __builtin_amdgcn_s_setprio(1);
      a11[0][c] = __builtin_amdgcn_mfma_f32_16x16x32_bf16(ai0, aj, a11[0][c], 0, 0, 0);
      a11[1][c] = __builtin_amdgcn_mfma_f32_16x16x32_bf16(ai1, aj, a11[1][c], 0, 0, 0);
      a12[0][c] = __builtin_amdgcn_mfma_f32_16x16x32_bf16(ai0, bj, a12[0][c], 0, 0, 0);
      a12[1][c] = __builtin_amdgcn_mfma_f32_16x16x32_bf16(ai1, bj, a12[1][c], 0, 0, 0);
      a22[0][c] = __builtin_amdgcn_mfma_f32_16x16x32_bf16(bi0, bj, a22[0][c], 0, 0, 0);
      a22[1][c] = __builtin_amdgcn_mfma_f32_16x16x32_bf16(bi1, bj, a22[1][c], 0, 0, 0);
      __builtin_amdgcn_s_setprio(0);
    }
    if (kc <= 13) bar_vm4();
    else if (kc == 14) bar_vm0();
    ro += 16384;
    if (ro == 49152) ro = 0;
  }
  float* rred = (float*)(shm + 16384);  // [4][128] row stats (buf1: dead)
  float* cred = rred + 512;             // [4][128] col stats
  rred[tid] = 0.f;
  rred[tid + 512] = 0.f;
  __syncthreads();
  float rs11[2][4] = {}, rm11[2][4] = {}, rs12[2][4] = {}, rm12[2][4] = {};
  float cs12[4] = {}, cm12[4] = {}, cs22[4] = {}, cm22[4] = {};
#pragma unroll
  for (int t = 0; t < 2; ++t)
#pragma unroll
    for (int c = 0; c < 4; ++c) {
      const int gj = j0 + jh * 64 + c * 16 + m16;
#pragma unroll
      for (int r = 0; r < 4; ++r) {
        const int gi = i0 + ig * 32 + t * 16 + quad * 4 + r;
        const float mv = (float)mask[(size_t)gi * NN + gj];
        const float e11 = __expf(a11[t][c][r] * INV_TAU);
        const float e12 = __expf(a12[t][c][r] * INV_TAU);
        const float e22 = __expf(a22[t][c][r] * INV_TAU);
        rs11[t][r] += e11;
        rm11[t][r] += e11 * mv;
        rs12[t][r] += e12;
        rm12[t][r] += e12 * mv;
        cs12[c] += e12;
        cm12[c] += e12 * mv;
        cs22[c] += e22;
        cm22[c] += e22 * mv;
      }
    }
#pragma unroll
  for (int t = 0; t < 2; ++t)
#pragma unroll
    for (int r = 0; r < 4; ++r) {
      float v0 = rs11[t][r], v1 = rm11[t][r], v2 = rs12[t][r], v3 = rm12[t][r];
#pragma unroll
      for (int o = 1; o < 16; o <<= 1) {
        v0 += __shfl_xor(v0, o, 64);
        v1 += __shfl_xor(v1, o, 64);
        v2 += __shfl_xor(v2, o, 64);
        v3 += __shfl_xor(v3, o, 64);
      }
      if (m16 == 0) {
        const int il = ig * 32 + t * 16 + quad * 4 + r;
        atomicAdd(&rred[0 * 128 + il], v0);
        atomicAdd(&rred[1 * 128 + il], v1);
        atomicAdd(&rred[2 * 128 + il], v2);
        atomicAdd(&rred[3 * 128 + il], v3);
      }
    }
#pragma unroll
  for (int c = 0; c < 4; ++c) {
    float v0 = cs12[c], v1 = cm12[c], v2 = cs22[c], v3 = cm22[c];
    v0 += __shfl_xor(v0, 16, 64); v0 += __shfl_xor(v0, 32, 64);
    v1 += __shfl_xor(v1, 16, 64); v1 += __shfl_xor(v1, 32, 64);
    v2 += __shfl_xor(v2, 16, 64); v2 += __shfl_xor(v2, 32, 64);
    v3 += __shfl_xor(v3, 16, 64); v3 += __shfl_xor(v3, 32, 64);
    if (lane < 16) {
      const int jl = jh * 64 + c * 16 + lane;
      atomicAdd(&cred[0 * 128 + jl], v0);
      atomicAdd(&cred[1 * 128 + jl], v1);
      atomicAdd(&cred[2 * 128 + jl], v2);
      atomicAdd(&cred[3 * 128 + jl], v3);
    }
  }
  __syncthreads();
  if (tid < 128) {
#pragma unroll
    for (int q = 0; q < 4; ++q)
      atomicAdd(&zb[q * NN + i0 + tid], rred[q * 128 + tid]);
  } else if (tid < 256) {
    const int jl = tid - 128;
#pragma unroll
    for (int q = 0; q < 4; ++q)
      atomicAdd(&zb[(4 + q) * NN + j0 + jl], cred[q * 128 + jl]);
  }
}

// ------- node 5: finalize (1 block) -----------------------------------------
__global__ __launch_bounds__(512) void fin(const float* __restrict__ zb,
                                           const float* __restrict__ plsP,
                                           const float* __restrict__ plsN,
                                           float* __restrict__ out) {
  const int tid = threadIdx.x;
  const int lane = tid & 63, w = tid >> 6;
  float S1 = 0.f, S2 = 0.f;
#pragma unroll
  for (int k = 0; k < 8; ++k) {
    const int i = tid + k * 512;
    const float r11 = zb[i], r11m = zb[NN + i];
    const float r12 = zb[2 * NN + i], r12m = zb[3 * NN + i];
    const float c12 = zb[4 * NN + i], c12m = zb[5 * NN + i];
    const float c22 = zb[6 * NN + i], c22m = zb[7 * NN + i];
    S1 += -logf(r12m / (r11 + r12 - r11m));
    S2 += -logf(c12m / (c22 + c12 - c22m));
  }
  float G = (tid < 64) ? (plsP[tid] + plsN[tid]) : 0.f;
  S1 = wave_sum(S1);
  S2 = wave_sum(S2);
  G = wave_sum(G);
  __shared__ float fr[3][8];
  if (lane == 0) { fr[0][w] = S1; fr[1][w] = S2; fr[2][w] = G; }
  __syncthreads();
  if (tid == 0) {
    float s1t = 0.f, s2t = 0.f, gt = 0.f;
    for (int q = 0; q < 8; ++q) {
      s1t += fr[0][q];
      s2t += fr[1][q];
      gt += fr[2][q];
    }
    const float local = 0.5f * (s1t + s2t) * (1.f / NN);
    const float glob = 0.25f * gt * (1.f / NN);
    out[0] = 0.5f * local + 0.5f * glob;
  }
}

extern "C" void kernel_launch(void* const* d_in, const int* in_sizes, int n_in,
                              void* d_out, int out_size, void* d_ws,
                              size_t ws_size, hipStream_t stream) {
  const float* z1 = (const float*)d_in[0];
  const float* z2 = (const float*)d_in[1];
  const float* lw1 = (const float*)d_in[2];
  const float* lb1 = (const float*)d_in[3];
  const float* la = (const float*)d_in[4];
  const float* lw2 = (const float*)d_in[5];
  const float* lb2 = (const float*)d_in[6];
  const float* gw1 = (const float*)d_in[7];
  const float* gb1 = (const float*)d_in[8];
  const float* ga = (const float*)d_in[9];
  const float* gw2 = (const float*)d_in[10];
  const float* gb2 = (const float*)d_in[11];
  const float* W = (const float*)d_in[12];
  const int* mask = (const int*)d_in[13];
  float* out = (float*)d_out;

  static bool attr_set = false;
  if (!attr_set) {
    (void)hipFuncSetAttribute(reinterpret_cast<const void*>(sim_mfma),
                              hipFuncAttributeMaxDynamicSharedMemorySize,
                              98304);
    (void)hipFuncSetAttribute(reinterpret_cast<const void*>(head_fused),
                              hipFuncAttributeMaxDynamicSharedMemorySize,
                              98304);
    attr_set = true;
  }

  const size_t ND = (size_t)NN * DD;
  u16* W1b = (u16*)d_ws;                  // [512*512] (W2b contiguous after)
  u16* NAb = W1b + 2 * 512 * 512;         // [2][N*D] bf16 normalized (na|nb)
  float* zbf = (float*)(NAb + 2 * ND);    // 8*NN
  float* pc1 = zbf + 8 * NN;              // [128][512]
  float* pc2 = pc1 + 128 * 512;           // [128][512]
  float* hg = pc2 + 128 * 512;            // [2][512]
  float* plsP = hg + 1024;                // 64
  float* plsN = plsP + 64;                // 64

  // 1) weights -> bf16 + zero zbf
  tobf16w<<<512, dim3(256), 0, stream>>>(lw1, lw2, W1b, zbf);
  // 2) fused head: convert + gemm1(PReLU) + gemm2 + L2norm (+ pc partials)
  head_fused<<<256, dim3(512), 98304, stream>>>(
      z1, z2, W1b, W1b + 512 * 512, lb1, la, lb2, NAb, pc1, pc2);
  // 3) global projector to hg (wide, race-free slices)
  mvh<<<128, dim3(256), 0, stream>>>(pc1, pc2, gw1, gb1, ga, gw2, gb2, hg);
  // 4) fused similarity + logsig partials (summ computed in-block)
  sim_mfma<<<dim3(32, 34), dim3(512), 98304, stream>>>(
      NAb, NAb + ND, mask, zbf, z1, z2, W, hg, plsP, plsN);
  // 5) finalize -> out[0]
  fin<<<1, dim3(512), 0, stream>>>(zbf, plsP, plsN, out);
}

// Round 11
// 285.218 us; speedup vs baseline: 1.1841x; 1.1841x over previous
//
#include <hip/hip_runtime.h>
#include <math.h>

#define NN 4096
#define DD 512
#define INV_TAU 5.0f
#define EPSV 1e-15f

typedef unsigned short u16;
typedef unsigned long long u64;
typedef __attribute__((ext_vector_type(8))) short short8;
typedef __attribute__((ext_vector_type(4))) float f32x4;

__device__ __forceinline__ void gld16(const void* g, void* l) {
  __builtin_amdgcn_global_load_lds(
      (const __attribute__((address_space(1))) unsigned int*)g,
      (__attribute__((address_space(3))) unsigned int*)l, 16, 0, 0);
}

// counted-vmcnt barriers (T3/T4)
__device__ __forceinline__ void bar_vm4() {
  asm volatile("s_waitcnt vmcnt(4) lgkmcnt(0)\n\ts_barrier" ::: "memory");
}
__device__ __forceinline__ void bar_vm2() {
  asm volatile("s_waitcnt vmcnt(2) lgkmcnt(0)\n\ts_barrier" ::: "memory");
}
__device__ __forceinline__ void bar_vm1() {
  asm volatile("s_waitcnt vmcnt(1) lgkmcnt(0)\n\ts_barrier" ::: "memory");
}
__device__ __forceinline__ void bar_vm0() {
  asm volatile("s_waitcnt vmcnt(0) lgkmcnt(0)\n\ts_barrier" ::: "memory");
}

__device__ __forceinline__ float bf2f(u16 u) {
  return __uint_as_float(((unsigned)u) << 16);
}
__device__ __forceinline__ u16 f2bf(float x) {  // RNE
  unsigned u = __float_as_uint(x);
  u += 0x7fff + ((u >> 16) & 1);
  return (u16)(u >> 16);
}

__device__ __forceinline__ float wave_sum(float v) {
#pragma unroll
  for (int o = 32; o > 0; o >>= 1) v += __shfl_down(v, o, 64);
  return v;
}

// ------- node 1: fp32->bf16 convert (lw1|lw2|z1|z2) + colmean partials -------
// blocks [0,4608): convert; [4608,4736): colmean partials; blocks 0..127 zero
// zbf. blocks [4736, 4736+npack): mask bitpack (only when workspace-gated in).
__global__ __launch_bounds__(256) void tobf16cm(
    const float* __restrict__ a, const float* __restrict__ b,
    const float* __restrict__ c, const float* __restrict__ d2,
    u16* __restrict__ o, float* __restrict__ pc1, float* __restrict__ pc2,
    float* __restrict__ zbf, const int* __restrict__ mask,
    u64* __restrict__ mpack) {
  const int bid = blockIdx.x, tid = threadIdx.x;
  if (bid >= 4736) {  // mask bitpack (gated)
    const int bp = bid - 4736;
    const int w = tid >> 6, lane = tid & 63;
#pragma unroll
    for (int it = 0; it < 32; ++it) {
      const size_t wi = ((size_t)bp * 4 + w) * 32 + it;
      const int v = mask[wi * 64 + lane];
      const u64 bb = __ballot(v != 0);
      if (lane == 0) mpack[wi] = bb;
    }
    return;
  }
  if (bid >= 4608) {  // colmean partials
    const int blk = bid - 4608;
    const int r0 = blk * 32;
    float a0 = 0.f, a1 = 0.f, c0 = 0.f, c1 = 0.f;
    for (int r = r0; r < r0 + 32; ++r) {
      const size_t ro = (size_t)r * DD;
      a0 += c[ro + tid];
      a1 += c[ro + 256 + tid];
      c0 += d2[ro + tid];
      c1 += d2[ro + 256 + tid];
    }
    pc1[blk * 512 + tid] = a0;
    pc1[blk * 512 + 256 + tid] = a1;
    pc2[blk * 512 + tid] = c0;
    pc2[blk * 512 + 256 + tid] = c1;
    return;
  }
  if (bid < 128) zbf[bid * 256 + tid] = 0.f;
  const int i = bid * 256 + tid;
  int j = i;
  const float* s;
  if (j < 65536) {
    s = a + (size_t)j * 4;
  } else {
    j -= 65536;
    if (j < 65536) {
      s = b + (size_t)j * 4;
    } else {
      j -= 65536;
      if (j < 524288) {
        s = c + (size_t)j * 4;
      } else {
        j -= 524288;
        s = d2 + (size_t)j * 4;
      }
    }
  }
  float4 v = *(const float4*)s;
  u64 pk = (u64)f2bf(v.x) | ((u64)f2bf(v.y) << 16) | ((u64)f2bf(v.z) << 32) |
           ((u64)f2bf(v.w) << 48);
  *(u64*)&o[(size_t)i * 4] = pk;
}

// ------- nodes 2-3: MFMA NT GEMM (proven) + leading mv blocks ---------------
template <int ACT>
__global__ __launch_bounds__(512) void gemm_mv(
    const u16* __restrict__ A, const u16* __restrict__ Bw,
    const float* __restrict__ bias, const float* __restrict__ alpha_p,
    u16* __restrict__ out, const float* __restrict__ Mw,
    const float* __restrict__ mx1, const float* __restrict__ mx2,
    const float* __restrict__ mbias, const float* __restrict__ mal,
    float* __restrict__ my1, float* __restrict__ my2) {
  __shared__ __align__(16) u16 sh[3 * 6144];
  __shared__ float svb[512];
  const int tid = threadIdx.x, w = tid >> 6, lane = tid & 63;
  if (blockIdx.x < 64) {  // ---- mv block ----
    const int mb = blockIdx.x;
    const int bz = mb >> 5, bx = mb & 31;
    const float* xin = bz ? mx2 : mx1;
    float* y = bz ? my2 : my1;
    if (ACT) {  // mv1: reduce pc[128][512] -> sv (4-way unrolled for ILP)
      float a0 = 0.f, a1 = 0.f, a2 = 0.f, a3 = 0.f;
      for (int b = 0; b < 128; b += 4) {
        a0 += xin[b * 512 + tid];
        a1 += xin[(b + 1) * 512 + tid];
        a2 += xin[(b + 2) * 512 + tid];
        a3 += xin[(b + 3) * 512 + tid];
      }
      svb[tid] = ((a0 + a1) + (a2 + a3)) * (1.f / NN);
    } else {
      svb[tid] = xin[tid];
    }
    __syncthreads();
#pragma unroll
    for (int rr = 0; rr < 2; ++rr) {
      const int row = bx * 16 + w * 2 + rr;
      float acc = 0.f;
#pragma unroll
      for (int q = 0; q < 8; ++q)
        acc = fmaf(Mw[(size_t)row * DD + lane + 64 * q], svb[lane + 64 * q],
                   acc);
      acc = wave_sum(acc);
      if (lane == 0) {
        acc += mbias[row];
        if (ACT) {
          const float al = mal[0];
          acc = (acc >= 0.f) ? acc : al * acc;
        }
        y[row] = acc;
      }
    }
    return;
  }
  // ---- GEMM block ----
  const int quad = lane >> 4, m16 = lane & 15;
  const int wi = w >> 1, wj = w & 1;
  const int bid2 = blockIdx.x - 64;
  const int xcd = bid2 & 7, idx = bid2 >> 3;
  const int i0 = (4 * xcd + (idx & 3)) * 128;
  const int j0 = ((idx >> 2) & 7) * 64;
  const int bz = idx >> 5;
  const u16* Ab = A + (size_t)bz * ((size_t)NN * DD);
  u16* ob = out + (size_t)bz * ((size_t)NN * DD);
  const int roff =
      (m16 >> 1) * 64 + (((((m16 & 1) << 2) | quad) ^ (m16 >> 1)) * 8);
  const int st = (lane & 7) ^ (lane >> 3);
  const int srow = 2 * (lane >> 3) + (st >> 2);
  const int scol = (st & 3) * 8;
  const u16* gs = (w < 4) ? Ab : Bw;
  const int grow0 = ((w < 4) ? i0 + 2 * w * 16 : j0 + (w - 4) * 16) + srow;
  const int doff0 = (w < 4) ? 2 * w * 512 : 4096 + (w - 4) * 512;
  auto stage = [&](int bo, int k) {
    const int kn = k * 32;
    gld16(&gs[(size_t)grow0 * DD + kn + scol], sh + bo + doff0);
    if (w < 4)
      gld16(&gs[(size_t)(grow0 + 16) * DD + kn + scol], sh + bo + doff0 + 512);
  };
  stage(0, 0);
  stage(6144, 1);
  if (w < 4) bar_vm2(); else bar_vm1();
  f32x4 acc[2][2] = {};
  int ro = 0;
  for (int kc = 0; kc < 16; ++kc) {
    if (kc <= 13) {
      int so = ro + 12288;
      if (so >= 18432) so -= 18432;
      stage(so, kc + 2);
    }
    const u16* As = sh + ro;
    const u16* Bs = sh + ro + 4096;
    short8 ar[2], br[2];
#pragma unroll
    for (int s = 0; s < 2; ++s) {
      ar[s] = *(const short8*)&As[(wi * 32 + s * 16) * 32 + roff];
      br[s] = *(const short8*)&Bs[(wj * 32 + s * 16) * 32 + roff];
    }
    __builtin_amdgcn_s_setprio(1);
#pragma unroll
    for (int si = 0; si < 2; ++si)
#pragma unroll
      for (int sj = 0; sj < 2; ++sj)
        acc[si][sj] = __builtin_amdgcn_mfma_f32_16x16x32_bf16(
            ar[si], br[sj], acc[si][sj], 0, 0, 0);
    __builtin_amdgcn_s_setprio(0);
    if (kc <= 13) {
      if (w < 4) bar_vm2(); else bar_vm1();
    } else if (kc == 14) {
      bar_vm0();
    }
    ro += 6144;
    if (ro == 18432) ro = 0;
  }
  const float al = ACT ? alpha_p[0] : 0.f;
#pragma unroll
  for (int si = 0; si < 2; ++si)
#pragma unroll
    for (int sj = 0; sj < 2; ++sj) {
      const int col = j0 + wj * 32 + sj * 16 + m16;
      const float bv = bias[col];
#pragma unroll
      for (int r = 0; r < 4; ++r) {
        const int row = i0 + wi * 32 + si * 16 + quad * 4 + r;
        float x = acc[si][sj][r] + bv;
        if (ACT) x = (x >= 0.f) ? x : al * x;
        ob[(size_t)row * DD + col] = f2bf(x);
      }
    }
}

// ------- node 4: row L2-normalize + leading mv3 blocks (proven r5) ----------
__global__ __launch_bounds__(256) void rownorm_mv(
    const u16* __restrict__ h, u16* __restrict__ o,
    const float* __restrict__ W, const float* __restrict__ hx1,
    const float* __restrict__ hx2, float* __restrict__ sm1,
    float* __restrict__ sm2) {
  const int bid = blockIdx.x, tid = threadIdx.x;
  const int lane = tid & 63, w = tid >> 6;
  if (bid < 256) {  // mv3
    const int bz = bid >> 7, bx = bid & 127;
    const float* x = bz ? hx2 : hx1;
    float* y = bz ? sm2 : sm1;
    const int row = bx * 4 + w;
    float acc = 0.f;
#pragma unroll
    for (int q = 0; q < 8; ++q)
      acc = fmaf(W[(size_t)row * DD + lane + 64 * q], x[lane + 64 * q], acc);
    acc = wave_sum(acc);
    if (lane == 0) y[row] = acc;
    return;
  }
  const int row = (bid - 256) * 4 + w;
  const size_t base = (size_t)row * DD + lane * 8;
  short8 v = *(const short8*)&h[base];
  float f[8];
  float s = 0.f;
#pragma unroll
  for (int j = 0; j < 8; ++j) {
    f[j] = bf2f((u16)v[j]);
    s += f[j] * f[j];
  }
  s = wave_sum(s);
  const float inv = 1.f / fmaxf(sqrtf(__shfl(s, 0, 64)), 1e-12f);
  short8 r;
#pragma unroll
  for (int j = 0; j < 8; ++j) r[j] = (short)f2bf(f[j] * inv);
  *(short8*)&o[base] = r;
}

// ------- node 5: fused similarity (EXACT r5 body; epilogue mask path chosen
// by mp!=null) + leading logsig blocks. grid (32, 34). ------------------------
__global__ __launch_bounds__(512) void sim_mfma(
    const u16* __restrict__ na, const u16* __restrict__ nb,
    const int* __restrict__ mask, const u64* __restrict__ mp,
    float* __restrict__ zb, const float* __restrict__ z1g,
    const float* __restrict__ z2g, const float* __restrict__ sm1,
    const float* __restrict__ sm2, float* __restrict__ plsP,
    float* __restrict__ plsN) {
  extern __shared__ __align__(16) u16 shm[];  // 96 KiB dynamic
  const int tid = threadIdx.x;
  const int w = tid >> 6, lane = tid & 63;
  if (blockIdx.y < 2) {  // ---- logsig partials: 64 blocks ----
    const int lx = blockIdx.y * 32 + blockIdx.x;
    const int bz = lx >> 5, bx5 = lx & 31;
    const float* z = bz ? z2g : z1g;
    const float* sp = bz ? sm2 : sm1;
    const float* sn = bz ? sm1 : sm2;
    float lp = 0.f, ln_ = 0.f;
    for (int k = 0; k < 16; ++k) {
      const int row = bx5 * 128 + w * 16 + k;
      float dp = 0.f, dn = 0.f;
#pragma unroll
      for (int t = 0; t < 8; ++t) {
        const float zv = z[(size_t)row * DD + lane + 64 * t];
        dp = fmaf(zv, sp[lane + 64 * t], dp);
        dn = fmaf(zv, sn[lane + 64 * t], dn);
      }
      dp = wave_sum(dp);
      dn = wave_sum(dn);
      if (lane == 0) {
        lp += -logf(1.f / (1.f + __expf(-dp)) + EPSV);
        ln_ += -logf(1.f - 1.f / (1.f + __expf(-dn)) + EPSV);
      }
    }
    float* red = (float*)shm;
    if (lane == 0) { red[w] = lp; red[8 + w] = ln_; }
    __syncthreads();
    if (tid == 0) {
      float sP = 0.f, sN = 0.f;
      for (int q = 0; q < 8; ++q) { sP += red[q]; sN += red[8 + q]; }
      plsP[lx] = sP;
      plsN[lx] = sN;
    }
    return;
  }
  const int quad = lane >> 4, m16 = lane & 15;
  const int ig = w & 3, jh = w >> 2;
  const int i0 = (blockIdx.y - 2) * 128, j0 = blockIdx.x * 128;
  const int roff =
      (m16 >> 1) * 64 + (((((m16 & 1) << 2) | quad) ^ (m16 >> 1)) * 8);
  const int st = (lane & 7) ^ (lane >> 3);
  const int srow = 2 * (lane >> 3) + (st >> 2);
  const int scol = (st & 3) * 8;
  const int p = w >> 1, rh = (w & 1) * 64;
  const u16* gs = (p & 1) ? nb : na;
  const int gr = ((p < 2) ? i0 : j0) + rh + srow;
  u16* dst0 = shm + p * 4096 + rh * 32;
  auto stage = [&](int bo, int k) {
    const int kn = k * 32;
#pragma unroll
    for (int rr = 0; rr < 64; rr += 16)
      gld16(&gs[(size_t)(gr + rr) * DD + kn + scol], dst0 + bo + rr * 32);
  };
  stage(0, 0);
  stage(16384, 1);
  bar_vm4();
  f32x4 a11[2][4] = {}, a12[2][4] = {}, a22[2][4] = {};
  int ro = 0;
  for (int kc = 0; kc < 16; ++kc) {
    if (kc <= 13) {
      int so = ro + 32768;
      if (so >= 49152) so -= 49152;
      stage(so, kc + 2);
    }
    const u16* Ai = shm + ro;
    const u16* Bi = shm + ro + 4096;
    const u16* Aj = shm + ro + 8192;
    const u16* Bj = shm + ro + 12288;
    short8 ai0 = *(const short8*)&Ai[(ig * 32) * 32 + roff];
    short8 ai1 = *(const short8*)&Ai[(ig * 32 + 16) * 32 + roff];
    short8 bi0 = *(const short8*)&Bi[(ig * 32) * 32 + roff];
    short8 bi1 = *(const short8*)&Bi[(ig * 32 + 16) * 32 + roff];
#pragma unroll
    for (int c = 0; c < 4; ++c) {
      short8 aj = *(const short8*)&Aj[(jh * 64 + c * 16) * 32 + roff];
      short8 bj = *(const short8*)&Bj[(jh * 64 + c * 16) * 32 + roff];
      __builtin_amdgcn_s_setprio(1);
      a11[0][c] = __builtin_amdgcn_mfma_f32_16x16x32_bf16(ai0, aj, a11[0][c], 0, 0, 0);
      a11[1][c] = __builtin_amdgcn_mfma_f32_16x16x32_bf16(ai1, aj, a11[1][c], 0, 0, 0);
      a12[0][c] = __builtin_amdgcn_mfma_f32_16x16x32_bf16(ai0, bj, a12[0][c], 0, 0, 0);
      a12[1][c] = __builtin_amdgcn_mfma_f32_16x16x32_bf16(ai1, bj, a12[1][c], 0, 0, 0);
      a22[0][c] = __builtin_amdgcn_mfma_f32_16x16x32_bf16(bi0, bj, a22[0][c], 0, 0, 0);
      a22[1][c] = __builtin_amdgcn_mfma_f32_16x16x32_bf16(bi1, bj, a22[1][c], 0, 0, 0);
      __builtin_amdgcn_s_setprio(0);
    }
    if (kc <= 13) bar_vm4();
    else if (kc == 14) bar_vm0();
    ro += 16384;
    if (ro == 49152) ro = 0;
  }
  float* rred = (float*)(shm + 16384);  // [4][128] row stats (buf1: dead)
  float* cred = rred + 512;             // [4][128] col stats
  rred[tid] = 0.f;
  rred[tid + 512] = 0.f;
  __syncthreads();
  float rs11[2][4] = {}, rm11[2][4] = {}, rs12[2][4] = {}, rm12[2][4] = {};
  float cs12[4] = {}, cm12[4] = {}, cs22[4] = {}, cm22[4] = {};
  if (mp) {  // bitpacked mask: 8 broadcast u64 loads (L2-resident 2 MB)
    const int mwcol = (j0 >> 6) + jh;
#pragma unroll
    for (int t = 0; t < 2; ++t)
#pragma unroll
      for (int r = 0; r < 4; ++r) {
        const int gi = i0 + ig * 32 + t * 16 + quad * 4 + r;
        const u64 mb = mp[(size_t)gi * 64 + mwcol];
#pragma unroll
        for (int c = 0; c < 4; ++c) {
          const float mv = (float)((mb >> (c * 16 + m16)) & 1ull);
          const float e11 = __expf(a11[t][c][r] * INV_TAU);
          const float e12 = __expf(a12[t][c][r] * INV_TAU);
          const float e22 = __expf(a22[t][c][r] * INV_TAU);
          rs11[t][r] += e11;
          rm11[t][r] += e11 * mv;
          rs12[t][r] += e12;
          rm12[t][r] += e12 * mv;
          cs12[c] += e12;
          cm12[c] += e12 * mv;
          cs22[c] += e22;
          cm22[c] += e22 * mv;
        }
      }
  } else {  // r5 path: direct int32 mask reads
#pragma unroll
    for (int t = 0; t < 2; ++t)
#pragma unroll
      for (int c = 0; c < 4; ++c) {
        const int gj = j0 + jh * 64 + c * 16 + m16;
#pragma unroll
        for (int r = 0; r < 4; ++r) {
          const int gi = i0 + ig * 32 + t * 16 + quad * 4 + r;
          const float mv = (float)mask[(size_t)gi * NN + gj];
          const float e11 = __expf(a11[t][c][r] * INV_TAU);
          const float e12 = __expf(a12[t][c][r] * INV_TAU);
          const float e22 = __expf(a22[t][c][r] * INV_TAU);
          rs11[t][r] += e11;
          rm11[t][r] += e11 * mv;
          rs12[t][r] += e12;
          rm12[t][r] += e12 * mv;
          cs12[c] += e12;
          cm12[c] += e12 * mv;
          cs22[c] += e22;
          cm22[c] += e22 * mv;
        }
      }
  }
#pragma unroll
  for (int t = 0; t < 2; ++t)
#pragma unroll
    for (int r = 0; r < 4; ++r) {
      float v0 = rs11[t][r], v1 = rm11[t][r], v2 = rs12[t][r], v3 = rm12[t][r];
#pragma unroll
      for (int o = 1; o < 16; o <<= 1) {
        v0 += __shfl_xor(v0, o, 64);
        v1 += __shfl_xor(v1, o, 64);
        v2 += __shfl_xor(v2, o, 64);
        v3 += __shfl_xor(v3, o, 64);
      }
      if (m16 == 0) {
        const int il = ig * 32 + t * 16 + quad * 4 + r;
        atomicAdd(&rred[0 * 128 + il], v0);
        atomicAdd(&rred[1 * 128 + il], v1);
        atomicAdd(&rred[2 * 128 + il], v2);
        atomicAdd(&rred[3 * 128 + il], v3);
      }
    }
#pragma unroll
  for (int c = 0; c < 4; ++c) {
    float v0 = cs12[c], v1 = cm12[c], v2 = cs22[c], v3 = cm22[c];
    v0 += __shfl_xor(v0, 16, 64); v0 += __shfl_xor(v0, 32, 64);
    v1 += __shfl_xor(v1, 16, 64); v1 += __shfl_xor(v1, 32, 64);
    v2 += __shfl_xor(v2, 16, 64); v2 += __shfl_xor(v2, 32, 64);
    v3 += __shfl_xor(v3, 16, 64); v3 += __shfl_xor(v3, 32, 64);
    if (lane < 16) {
      const int jl = jh * 64 + c * 16 + lane;
      atomicAdd(&cred[0 * 128 + jl], v0);
      atomicAdd(&cred[1 * 128 + jl], v1);
      atomicAdd(&cred[2 * 128 + jl], v2);
      atomicAdd(&cred[3 * 128 + jl], v3);
    }
  }
  __syncthreads();
  if (tid < 128) {
#pragma unroll
    for (int q = 0; q < 4; ++q)
      atomicAdd(&zb[q * NN + i0 + tid], rred[q * 128 + tid]);
  } else if (tid < 256) {
    const int jl = tid - 128;
#pragma unroll
    for (int q = 0; q < 4; ++q)
      atomicAdd(&zb[(4 + q) * NN + j0 + jl], cred[q * 128 + jl]);
  }
}

// ------- node 6: finalize (1 block) -----------------------------------------
__global__ __launch_bounds__(512) void fin(const float* __restrict__ zb,
                                           const float* __restrict__ plsP,
                                           const float* __restrict__ plsN,
                                           float* __restrict__ out) {
  const int tid = threadIdx.x;
  const int lane = tid & 63, w = tid >> 6;
  float S1 = 0.f, S2 = 0.f;
#pragma unroll
  for (int k = 0; k < 8; ++k) {
    const int i = tid + k * 512;
    const float r11 = zb[i], r11m = zb[NN + i];
    const float r12 = zb[2 * NN + i], r12m = zb[3 * NN + i];
    const float c12 = zb[4 * NN + i], c12m = zb[5 * NN + i];
    const float c22 = zb[6 * NN + i], c22m = zb[7 * NN + i];
    S1 += -logf(r12m / (r11 + r12 - r11m));
    S2 += -logf(c12m / (c22 + c12 - c22m));
  }
  float G = (tid < 64) ? (plsP[tid] + plsN[tid]) : 0.f;
  S1 = wave_sum(S1);
  S2 = wave_sum(S2);
  G = wave_sum(G);
  __shared__ float fr[3][8];
  if (lane == 0) { fr[0][w] = S1; fr[1][w] = S2; fr[2][w] = G; }
  __syncthreads();
  if (tid == 0) {
    float s1t = 0.f, s2t = 0.f, gt = 0.f;
    for (int q = 0; q < 8; ++q) {
      s1t += fr[0][q];
      s2t += fr[1][q];
      gt += fr[2][q];
    }
    const float local = 0.5f * (s1t + s2t) * (1.f / NN);
    const float glob = 0.25f * gt * (1.f / NN);
    out[0] = 0.5f * local + 0.5f * glob;
  }
}

extern "C" void kernel_launch(void* const* d_in, const int* in_sizes, int n_in,
                              void* d_out, int out_size, void* d_ws,
                              size_t ws_size, hipStream_t stream) {
  const float* z1 = (const float*)d_in[0];
  const float* z2 = (const float*)d_in[1];
  const float* lw1 = (const float*)d_in[2];
  const float* lb1 = (const float*)d_in[3];
  const float* la = (const float*)d_in[4];
  const float* lw2 = (const float*)d_in[5];
  const float* lb2 = (const float*)d_in[6];
  const float* gw1 = (const float*)d_in[7];
  const float* gb1 = (const float*)d_in[8];
  const float* ga = (const float*)d_in[9];
  const float* gw2 = (const float*)d_in[10];
  const float* gb2 = (const float*)d_in[11];
  const float* W = (const float*)d_in[12];
  const int* mask = (const int*)d_in[13];
  float* out = (float*)d_out;

  static bool attr_set = false;
  if (!attr_set) {
    (void)hipFuncSetAttribute(reinterpret_cast<const void*>(sim_mfma),
                              hipFuncAttributeMaxDynamicSharedMemorySize,
                              98304);
    attr_set = true;
  }

  const size_t ND = (size_t)NN * DD;
  u16* W1b = (u16*)d_ws;                  // [512*512]
  u16* W2b = W1b + 512 * 512;             // [512*512]
  u16* Ab = W1b + 2 * 512 * 512;          // [2][N*D] bf16
  u16* Bb = Ab + 2 * ND;                  // [2][N*D] bf16
  float* zbf = (float*)(Bb + 2 * ND);     // 8*NN
  float* pc1 = zbf + 8 * NN;              // [128][512]
  float* pc2 = pc1 + 128 * 512;           // [128][512]
  float* t1 = pc2 + 128 * 512;            // 512
  float* t2 = t1 + 512;                   // 512
  float* hg1 = t2 + 512;                  // 512
  float* hg2 = hg1 + 512;                 // 512
  float* summ1 = hg2 + 512;               // 512
  float* summ2 = summ1 + 512;             // 512
  float* plsP = summ2 + 512;              // 64
  float* plsN = plsP + 64;                // 64
  u64* mpack = (u64*)(plsN + 64);         // 262144 u64 = 2 MB (gated)

  // workspace gate: bitpack only if d_ws provably holds mpack (r6 lesson:
  // never extend the footprint blindly).
  const size_t need = (size_t)((char*)(mpack + 262144) - (char*)d_ws);
  const bool packed = (ws_size >= need);
  const int grid1 = packed ? (4736 + 2048) : 4736;

  // 1) convert + colmean partials + zero zbf (+ gated mask bitpack)
  tobf16cm<<<grid1, dim3(256), 0, stream>>>(lw1, lw2, z1, z2, W1b, pc1, pc2,
                                            zbf, mask, mpack);
  // 2) layer-1 GEMM (PReLU) + mv1 (pc -> t)
  gemm_mv<1><<<576, dim3(512), 0, stream>>>(Ab, W1b, lb1, la, Bb, gw1, pc1,
                                            pc2, gb1, ga, t1, t2);
  // 3) layer-2 GEMM + mv2 (t -> hg)
  gemm_mv<0><<<576, dim3(512), 0, stream>>>(Bb, W2b, lb2, la, Ab, gw2, t1, t2,
                                            gb2, nullptr, hg1, hg2);
  // 4) row L2-normalize + mv3 (hg -> summ)
  rownorm_mv<<<2304, dim3(256), 0, stream>>>(Ab, Bb, W, hg1, hg2, summ1,
                                             summ2);
  // 5) fused similarity (bitpacked mask if gated) + logsig partials
  sim_mfma<<<dim3(32, 34), dim3(512), 98304, stream>>>(
      Bb, Bb + ND, mask, packed ? mpack : (const u64*)nullptr, zbf, z1, z2,
      summ1, summ2, plsP, plsN);
  // 6) finalize -> out[0]
  fin<<<1, dim3(512), 0, stream>>>(zbf, plsP, plsN, out);
}

// Round 12
// 260.041 us; speedup vs baseline: 1.2987x; 1.0968x over previous
//
#include <hip/hip_runtime.h>
#include <math.h>

#define NN 4096
#define DD 512
#define INV_TAU 5.0f
#define EPSV 1e-15f

typedef unsigned short u16;
typedef unsigned long long u64;
typedef __attribute__((ext_vector_type(8))) short short8;
typedef __attribute__((ext_vector_type(4))) float f32x4;

__device__ __forceinline__ void gld16(const void* g, void* l) {
  __builtin_amdgcn_global_load_lds(
      (const __attribute__((address_space(1))) unsigned int*)g,
      (__attribute__((address_space(3))) unsigned int*)l, 16, 0, 0);
}

// counted-vmcnt barriers (T3/T4)
__device__ __forceinline__ void bar_vm4() {
  asm volatile("s_waitcnt vmcnt(4) lgkmcnt(0)\n\ts_barrier" ::: "memory");
}
__device__ __forceinline__ void bar_vm2() {
  asm volatile("s_waitcnt vmcnt(2) lgkmcnt(0)\n\ts_barrier" ::: "memory");
}
__device__ __forceinline__ void bar_vm1() {
  asm volatile("s_waitcnt vmcnt(1) lgkmcnt(0)\n\ts_barrier" ::: "memory");
}
__device__ __forceinline__ void bar_vm0() {
  asm volatile("s_waitcnt vmcnt(0) lgkmcnt(0)\n\ts_barrier" ::: "memory");
}

__device__ __forceinline__ float bf2f(u16 u) {
  return __uint_as_float(((unsigned)u) << 16);
}
__device__ __forceinline__ u16 f2bf(float x) {  // RNE
  unsigned u = __float_as_uint(x);
  u += 0x7fff + ((u >> 16) & 1);
  return (u16)(u >> 16);
}

__device__ __forceinline__ float wave_sum(float v) {
#pragma unroll
  for (int o = 32; o > 0; o >>= 1) v += __shfl_down(v, o, 64);
  return v;
}

// agent-scope atomic load/store: read/write the device coherence point
// (bypasses L1 / per-XCD-L2 staleness) — r3-proven read path, no fences.
__device__ __forceinline__ float ldz(const float* p) {
  return __hip_atomic_load(p, __ATOMIC_RELAXED, __HIP_MEMORY_SCOPE_AGENT);
}
__device__ __forceinline__ void stz(float* p, float v) {
  __hip_atomic_store(p, v, __ATOMIC_RELAXED, __HIP_MEMORY_SCOPE_AGENT);
}

// last-block finalize: local InfoNCE over zb + logsig partial sums -> out[0].
// 512 threads. All inputs written via atomics/agent-stores by prior blocks.
__device__ __forceinline__ void fin_run(const float* zb, const float* plsP,
                                        const float* plsN, float* out,
                                        int tid) {
  const int lane = tid & 63, w = tid >> 6;
  float S1 = 0.f, S2 = 0.f;
#pragma unroll
  for (int k = 0; k < 8; ++k) {
    const int i = tid + k * 512;
    const float r11 = ldz(&zb[i]), r11m = ldz(&zb[NN + i]);
    const float r12 = ldz(&zb[2 * NN + i]), r12m = ldz(&zb[3 * NN + i]);
    const float c12 = ldz(&zb[4 * NN + i]), c12m = ldz(&zb[5 * NN + i]);
    const float c22 = ldz(&zb[6 * NN + i]), c22m = ldz(&zb[7 * NN + i]);
    S1 += -logf(r12m / (r11 + r12 - r11m));
    S2 += -logf(c12m / (c22 + c12 - c22m));
  }
  float G = (tid < 64) ? (ldz(&plsP[tid]) + ldz(&plsN[tid])) : 0.f;
  S1 = wave_sum(S1);
  S2 = wave_sum(S2);
  G = wave_sum(G);
  __shared__ float fr[3][8];
  if (lane == 0) { fr[0][w] = S1; fr[1][w] = S2; fr[2][w] = G; }
  __syncthreads();
  if (tid == 0) {
    float s1t = 0.f, s2t = 0.f, gt = 0.f;
    for (int q = 0; q < 8; ++q) {
      s1t += fr[0][q];
      s2t += fr[1][q];
      gt += fr[2][q];
    }
    const float local = 0.5f * (s1t + s2t) * (1.f / NN);
    const float glob = 0.25f * gt * (1.f / NN);
    out[0] = 0.5f * local + 0.5f * glob;
  }
}

// ------- node 1: fp32->bf16 convert (lw1|lw2|z1|z2) + colmean partials -------
// blocks [0,4608): convert; [4608,4736): colmean partials; blocks 0..127 zero
// zbf; block 0 zeroes ctr.
__global__ __launch_bounds__(256) void tobf16cm(
    const float* __restrict__ a, const float* __restrict__ b,
    const float* __restrict__ c, const float* __restrict__ d2,
    u16* __restrict__ o, float* __restrict__ pc1, float* __restrict__ pc2,
    float* __restrict__ zbf, int* __restrict__ ctr) {
  const int bid = blockIdx.x, tid = threadIdx.x;
  if (bid >= 4608) {  // colmean partials
    const int blk = bid - 4608;
    const int r0 = blk * 32;
    float a0 = 0.f, a1 = 0.f, c0 = 0.f, c1 = 0.f;
    for (int r = r0; r < r0 + 32; ++r) {
      const size_t ro = (size_t)r * DD;
      a0 += c[ro + tid];
      a1 += c[ro + 256 + tid];
      c0 += d2[ro + tid];
      c1 += d2[ro + 256 + tid];
    }
    pc1[blk * 512 + tid] = a0;
    pc1[blk * 512 + 256 + tid] = a1;
    pc2[blk * 512 + tid] = c0;
    pc2[blk * 512 + 256 + tid] = c1;
    return;
  }
  if (bid == 0 && tid == 0) ctr[0] = 0;
  if (bid < 128) zbf[bid * 256 + tid] = 0.f;
  const int i = bid * 256 + tid;
  int j = i;
  const float* s;
  if (j < 65536) {
    s = a + (size_t)j * 4;
  } else {
    j -= 65536;
    if (j < 65536) {
      s = b + (size_t)j * 4;
    } else {
      j -= 65536;
      if (j < 524288) {
        s = c + (size_t)j * 4;
      } else {
        j -= 524288;
        s = d2 + (size_t)j * 4;
      }
    }
  }
  float4 v = *(const float4*)s;
  u64 pk = (u64)f2bf(v.x) | ((u64)f2bf(v.y) << 16) | ((u64)f2bf(v.z) << 32) |
           ((u64)f2bf(v.w) << 48);
  *(u64*)&o[(size_t)i * 4] = pk;
}

// ------- nodes 2-3: MFMA NT GEMM (proven) + leading mv blocks ---------------
template <int ACT>
__global__ __launch_bounds__(512) void gemm_mv(
    const u16* __restrict__ A, const u16* __restrict__ Bw,
    const float* __restrict__ bias, const float* __restrict__ alpha_p,
    u16* __restrict__ out, const float* __restrict__ Mw,
    const float* __restrict__ mx1, const float* __restrict__ mx2,
    const float* __restrict__ mbias, const float* __restrict__ mal,
    float* __restrict__ my1, float* __restrict__ my2) {
  __shared__ __align__(16) u16 sh[3 * 6144];
  __shared__ float svb[512];
  const int tid = threadIdx.x, w = tid >> 6, lane = tid & 63;
  if (blockIdx.x < 64) {  // ---- mv block ----
    const int mb = blockIdx.x;
    const int bz = mb >> 5, bx = mb & 31;
    const float* xin = bz ? mx2 : mx1;
    float* y = bz ? my2 : my1;
    if (ACT) {  // mv1: reduce pc[128][512] -> sv (4-way unrolled for ILP)
      float a0 = 0.f, a1 = 0.f, a2 = 0.f, a3 = 0.f;
      for (int b = 0; b < 128; b += 4) {
        a0 += xin[b * 512 + tid];
        a1 += xin[(b + 1) * 512 + tid];
        a2 += xin[(b + 2) * 512 + tid];
        a3 += xin[(b + 3) * 512 + tid];
      }
      svb[tid] = ((a0 + a1) + (a2 + a3)) * (1.f / NN);
    } else {
      svb[tid] = xin[tid];
    }
    __syncthreads();
#pragma unroll
    for (int rr = 0; rr < 2; ++rr) {
      const int row = bx * 16 + w * 2 + rr;
      float acc = 0.f;
#pragma unroll
      for (int q = 0; q < 8; ++q)
        acc = fmaf(Mw[(size_t)row * DD + lane + 64 * q], svb[lane + 64 * q],
                   acc);
      acc = wave_sum(acc);
      if (lane == 0) {
        acc += mbias[row];
        if (ACT) {
          const float al = mal[0];
          acc = (acc >= 0.f) ? acc : al * acc;
        }
        y[row] = acc;
      }
    }
    return;
  }
  // ---- GEMM block ----
  const int quad = lane >> 4, m16 = lane & 15;
  const int wi = w >> 1, wj = w & 1;
  const int bid2 = blockIdx.x - 64;
  const int xcd = bid2 & 7, idx = bid2 >> 3;
  const int i0 = (4 * xcd + (idx & 3)) * 128;
  const int j0 = ((idx >> 2) & 7) * 64;
  const int bz = idx >> 5;
  const u16* Ab = A + (size_t)bz * ((size_t)NN * DD);
  u16* ob = out + (size_t)bz * ((size_t)NN * DD);
  const int roff =
      (m16 >> 1) * 64 + (((((m16 & 1) << 2) | quad) ^ (m16 >> 1)) * 8);
  const int st = (lane & 7) ^ (lane >> 3);
  const int srow = 2 * (lane >> 3) + (st >> 2);
  const int scol = (st & 3) * 8;
  const u16* gs = (w < 4) ? Ab : Bw;
  const int grow0 = ((w < 4) ? i0 + 2 * w * 16 : j0 + (w - 4) * 16) + srow;
  const int doff0 = (w < 4) ? 2 * w * 512 : 4096 + (w - 4) * 512;
  auto stage = [&](int bo, int k) {
    const int kn = k * 32;
    gld16(&gs[(size_t)grow0 * DD + kn + scol], sh + bo + doff0);
    if (w < 4)
      gld16(&gs[(size_t)(grow0 + 16) * DD + kn + scol], sh + bo + doff0 + 512);
  };
  stage(0, 0);
  stage(6144, 1);
  if (w < 4) bar_vm2(); else bar_vm1();
  f32x4 acc[2][2] = {};
  int ro = 0;
  for (int kc = 0; kc < 16; ++kc) {
    if (kc <= 13) {
      int so = ro + 12288;
      if (so >= 18432) so -= 18432;
      stage(so, kc + 2);
    }
    const u16* As = sh + ro;
    const u16* Bs = sh + ro + 4096;
    short8 ar[2], br[2];
#pragma unroll
    for (int s = 0; s < 2; ++s) {
      ar[s] = *(const short8*)&As[(wi * 32 + s * 16) * 32 + roff];
      br[s] = *(const short8*)&Bs[(wj * 32 + s * 16) * 32 + roff];
    }
    __builtin_amdgcn_s_setprio(1);
#pragma unroll
    for (int si = 0; si < 2; ++si)
#pragma unroll
      for (int sj = 0; sj < 2; ++sj)
        acc[si][sj] = __builtin_amdgcn_mfma_f32_16x16x32_bf16(
            ar[si], br[sj], acc[si][sj], 0, 0, 0);
    __builtin_amdgcn_s_setprio(0);
    if (kc <= 13) {
      if (w < 4) bar_vm2(); else bar_vm1();
    } else if (kc == 14) {
      bar_vm0();
    }
    ro += 6144;
    if (ro == 18432) ro = 0;
  }
  const float al = ACT ? alpha_p[0] : 0.f;
#pragma unroll
  for (int si = 0; si < 2; ++si)
#pragma unroll
    for (int sj = 0; sj < 2; ++sj) {
      const int col = j0 + wj * 32 + sj * 16 + m16;
      const float bv = bias[col];
#pragma unroll
      for (int r = 0; r < 4; ++r) {
        const int row = i0 + wi * 32 + si * 16 + quad * 4 + r;
        float x = acc[si][sj][r] + bv;
        if (ACT) x = (x >= 0.f) ? x : al * x;
        ob[(size_t)row * DD + col] = f2bf(x);
      }
    }
}

// ------- node 4: row L2-normalize + leading mv3 blocks (proven r5) ----------
__global__ __launch_bounds__(256) void rownorm_mv(
    const u16* __restrict__ h, u16* __restrict__ o,
    const float* __restrict__ W, const float* __restrict__ hx1,
    const float* __restrict__ hx2, float* __restrict__ sm1,
    float* __restrict__ sm2) {
  const int bid = blockIdx.x, tid = threadIdx.x;
  const int lane = tid & 63, w = tid >> 6;
  if (bid < 256) {  // mv3
    const int bz = bid >> 7, bx = bid & 127;
    const float* x = bz ? hx2 : hx1;
    float* y = bz ? sm2 : sm1;
    const int row = bx * 4 + w;
    float acc = 0.f;
#pragma unroll
    for (int q = 0; q < 8; ++q)
      acc = fmaf(W[(size_t)row * DD + lane + 64 * q], x[lane + 64 * q], acc);
    acc = wave_sum(acc);
    if (lane == 0) y[row] = acc;
    return;
  }
  const int row = (bid - 256) * 4 + w;
  const size_t base = (size_t)row * DD + lane * 8;
  short8 v = *(const short8*)&h[base];
  float f[8];
  float s = 0.f;
#pragma unroll
  for (int j = 0; j < 8; ++j) {
    f[j] = bf2f((u16)v[j]);
    s += f[j] * f[j];
  }
  s = wave_sum(s);
  const float inv = 1.f / fmaxf(sqrtf(__shfl(s, 0, 64)), 1e-12f);
  short8 r;
#pragma unroll
  for (int j = 0; j < 8; ++j) r[j] = (short)f2bf(f[j] * inv);
  *(short8*)&o[base] = r;
}

// ------- node 5: fused similarity (EXACT r5 body) + leading logsig blocks +
// LAST-BLOCK finalize (fence-free: waitcnt-ordered atomic ticket). ------------
__global__ __launch_bounds__(512) void sim_mfma(
    const u16* __restrict__ na, const u16* __restrict__ nb,
    const int* __restrict__ mask, float* __restrict__ zb,
    const float* __restrict__ z1g, const float* __restrict__ z2g,
    const float* __restrict__ sm1, const float* __restrict__ sm2,
    float* __restrict__ plsP, float* __restrict__ plsN,
    int* __restrict__ ctr, float* __restrict__ out) {
  extern __shared__ __align__(16) u16 shm[];  // 96 KiB dynamic
  __shared__ int lastf;
  const int tid = threadIdx.x;
  const int w = tid >> 6, lane = tid & 63;
  if (blockIdx.y < 2) {  // ---- logsig partials: 64 blocks ----
    const int lx = blockIdx.y * 32 + blockIdx.x;
    const int bz = lx >> 5, bx5 = lx & 31;
    const float* z = bz ? z2g : z1g;
    const float* sp = bz ? sm2 : sm1;
    const float* sn = bz ? sm1 : sm2;
    float lp = 0.f, ln_ = 0.f;
    for (int k = 0; k < 16; ++k) {
      const int row = bx5 * 128 + w * 16 + k;
      float dp = 0.f, dn = 0.f;
#pragma unroll
      for (int t = 0; t < 8; ++t) {
        const float zv = z[(size_t)row * DD + lane + 64 * t];
        dp = fmaf(zv, sp[lane + 64 * t], dp);
        dn = fmaf(zv, sn[lane + 64 * t], dn);
      }
      dp = wave_sum(dp);
      dn = wave_sum(dn);
      if (lane == 0) {
        lp += -logf(1.f / (1.f + __expf(-dp)) + EPSV);
        ln_ += -logf(1.f - 1.f / (1.f + __expf(-dn)) + EPSV);
      }
    }
    float* red = (float*)shm;
    if (lane == 0) { red[w] = lp; red[8 + w] = ln_; }
    __syncthreads();
    if (tid == 0) {
      float sP = 0.f, sN = 0.f;
      for (int q = 0; q < 8; ++q) { sP += red[q]; sN += red[8 + q]; }
      stz(&plsP[lx], sP);  // agent-scope store: visible at coherence point
      stz(&plsN[lx], sN);
    }
    // order own stores before ticket, then tick
    asm volatile("s_waitcnt vmcnt(0)" ::: "memory");
    __syncthreads();
    if (tid == 0) lastf = (atomicAdd(ctr, 1) == 1087) ? 1 : 0;
    __syncthreads();
    if (lastf) fin_run(zb, plsP, plsN, out, tid);
    return;
  }
  const int quad = lane >> 4, m16 = lane & 15;
  const int ig = w & 3, jh = w >> 2;
  const int i0 = (blockIdx.y - 2) * 128, j0 = blockIdx.x * 128;
  const int roff =
      (m16 >> 1) * 64 + (((((m16 & 1) << 2) | quad) ^ (m16 >> 1)) * 8);
  const int st = (lane & 7) ^ (lane >> 3);
  const int srow = 2 * (lane >> 3) + (st >> 2);
  const int scol = (st & 3) * 8;
  const int p = w >> 1, rh = (w & 1) * 64;
  const u16* gs = (p & 1) ? nb : na;
  const int gr = ((p < 2) ? i0 : j0) + rh + srow;
  u16* dst0 = shm + p * 4096 + rh * 32;
  auto stage = [&](int bo, int k) {
    const int kn = k * 32;
#pragma unroll
    for (int rr = 0; rr < 64; rr += 16)
      gld16(&gs[(size_t)(gr + rr) * DD + kn + scol], dst0 + bo + rr * 32);
  };
  stage(0, 0);
  stage(16384, 1);
  bar_vm4();
  f32x4 a11[2][4] = {}, a12[2][4] = {}, a22[2][4] = {};
  int ro = 0;
  for (int kc = 0; kc < 16; ++kc) {
    if (kc <= 13) {
      int so = ro + 32768;
      if (so >= 49152) so -= 49152;
      stage(so, kc + 2);
    }
    const u16* Ai = shm + ro;
    const u16* Bi = shm + ro + 4096;
    const u16* Aj = shm + ro + 8192;
    const u16* Bj = shm + ro + 12288;
    short8 ai0 = *(const short8*)&Ai[(ig * 32) * 32 + roff];
    short8 ai1 = *(const short8*)&Ai[(ig * 32 + 16) * 32 + roff];
    short8 bi0 = *(const short8*)&Bi[(ig * 32) * 32 + roff];
    short8 bi1 = *(const short8*)&Bi[(ig * 32 + 16) * 32 + roff];
#pragma unroll
    for (int c = 0; c < 4; ++c) {
      short8 aj = *(const short8*)&Aj[(jh * 64 + c * 16) * 32 + roff];
      short8 bj = *(const short8*)&Bj[(jh * 64 + c * 16) * 32 + roff];
      __builtin_amdgcn_s_setprio(1);
      a11[0][c] = __builtin_amdgcn_mfma_f32_16x16x32_bf16(ai0, aj, a11[0][c], 0, 0, 0);
      a11[1][c] = __builtin_amdgcn_mfma_f32_16x16x32_bf16(ai1, aj, a11[1][c], 0, 0, 0);
      a12[0][c] = __builtin_amdgcn_mfma_f32_16x16x32_bf16(ai0, bj, a12[0][c], 0, 0, 0);
      a12[1][c] = __builtin_amdgcn_mfma_f32_16x16x32_bf16(ai1, bj, a12[1][c], 0, 0, 0);
      a22[0][c] = __builtin_amdgcn_mfma_f32_16x16x32_bf16(bi0, bj, a22[0][c], 0, 0, 0);
      a22[1][c] = __builtin_amdgcn_mfma_f32_16x16x32_bf16(bi1, bj, a22[1][c], 0, 0, 0);
      __builtin_amdgcn_s_setprio(0);
    }
    if (kc <= 13) bar_vm4();
    else if (kc == 14) bar_vm0();
    ro += 16384;
    if (ro == 49152) ro = 0;
  }
  float* rred = (float*)(shm + 16384);  // [4][128] row stats (buf1: dead)
  float* cred = rred + 512;             // [4][128] col stats
  rred[tid] = 0.f;
  rred[tid + 512] = 0.f;
  __syncthreads();
  float rs11[2][4] = {}, rm11[2][4] = {}, rs12[2][4] = {}, rm12[2][4] = {};
  float cs12[4] = {}, cm12[4] = {}, cs22[4] = {}, cm22[4] = {};
#pragma unroll
  for (int t = 0; t < 2; ++t)
#pragma unroll
    for (int c = 0; c < 4; ++c) {
      const int gj = j0 + jh * 64 + c * 16 + m16;
#pragma unroll
      for (int r = 0; r < 4; ++r) {
        const int gi = i0 + ig * 32 + t * 16 + quad * 4 + r;
        const float mv = (float)mask[(size_t)gi * NN + gj];
        const float e11 = __expf(a11[t][c][r] * INV_TAU);
        const float e12 = __expf(a12[t][c][r] * INV_TAU);
        const float e22 = __expf(a22[t][c][r] * INV_TAU);
        rs11[t][r] += e11;
        rm11[t][r] += e11 * mv;
        rs12[t][r] += e12;
        rm12[t][r] += e12 * mv;
        cs12[c] += e12;
        cm12[c] += e12 * mv;
        cs22[c] += e22;
        cm22[c] += e22 * mv;
      }
    }
#pragma unroll
  for (int t = 0; t < 2; ++t)
#pragma unroll
    for (int r = 0; r < 4; ++r) {
      float v0 = rs11[t][r], v1 = rm11[t][r], v2 = rs12[t][r], v3 = rm12[t][r];
#pragma unroll
      for (int o = 1; o < 16; o <<= 1) {
        v0 += __shfl_xor(v0, o, 64);
        v1 += __shfl_xor(v1, o, 64);
        v2 += __shfl_xor(v2, o, 64);
        v3 += __shfl_xor(v3, o, 64);
      }
      if (m16 == 0) {
        const int il = ig * 32 + t * 16 + quad * 4 + r;
        atomicAdd(&rred[0 * 128 + il], v0);
        atomicAdd(&rred[1 * 128 + il], v1);
        atomicAdd(&rred[2 * 128 + il], v2);
        atomicAdd(&rred[3 * 128 + il], v3);
      }
    }
#pragma unroll
  for (int c = 0; c < 4; ++c) {
    float v0 = cs12[c], v1 = cm12[c], v2 = cs22[c], v3 = cm22[c];
    v0 += __shfl_xor(v0, 16, 64); v0 += __shfl_xor(v0, 32, 64);
    v1 += __shfl_xor(v1, 16, 64); v1 += __shfl_xor(v1, 32, 64);
    v2 += __shfl_xor(v2, 16, 64); v2 += __shfl_xor(v2, 32, 64);
    v3 += __shfl_xor(v3, 16, 64); v3 += __shfl_xor(v3, 32, 64);
    if (lane < 16) {
      const int jl = jh * 64 + c * 16 + lane;
      atomicAdd(&cred[0 * 128 + jl], v0);
      atomicAdd(&cred[1 * 128 + jl], v1);
      atomicAdd(&cred[2 * 128 + jl], v2);
      atomicAdd(&cred[3 * 128 + jl], v3);
    }
  }
  __syncthreads();
  if (tid < 128) {
#pragma unroll
    for (int q = 0; q < 4; ++q)
      atomicAdd(&zb[q * NN + i0 + tid], rred[q * 128 + tid]);
  } else if (tid < 256) {
    const int jl = tid - 128;
#pragma unroll
    for (int q = 0; q < 4; ++q)
      atomicAdd(&zb[(4 + q) * NN + j0 + jl], cred[q * 128 + jl]);
  }
  // ---- fence-free last-block ticket: own atomics drained, then tick ----
  asm volatile("s_waitcnt vmcnt(0)" ::: "memory");
  __syncthreads();
  if (tid == 0) lastf = (atomicAdd(ctr, 1) == 1087) ? 1 : 0;
  __syncthreads();
  if (lastf) fin_run(zb, plsP, plsN, out, tid);
}

extern "C" void kernel_launch(void* const* d_in, const int* in_sizes, int n_in,
                              void* d_out, int out_size, void* d_ws,
                              size_t ws_size, hipStream_t stream) {
  const float* z1 = (const float*)d_in[0];
  const float* z2 = (const float*)d_in[1];
  const float* lw1 = (const float*)d_in[2];
  const float* lb1 = (const float*)d_in[3];
  const float* la = (const float*)d_in[4];
  const float* lw2 = (const float*)d_in[5];
  const float* lb2 = (const float*)d_in[6];
  const float* gw1 = (const float*)d_in[7];
  const float* gb1 = (const float*)d_in[8];
  const float* ga = (const float*)d_in[9];
  const float* gw2 = (const float*)d_in[10];
  const float* gb2 = (const float*)d_in[11];
  const float* W = (const float*)d_in[12];
  const int* mask = (const int*)d_in[13];
  float* out = (float*)d_out;

  static bool attr_set = false;
  if (!attr_set) {
    (void)hipFuncSetAttribute(reinterpret_cast<const void*>(sim_mfma),
                              hipFuncAttributeMaxDynamicSharedMemorySize,
                              98304);
    attr_set = true;
  }

  const size_t ND = (size_t)NN * DD;
  u16* W1b = (u16*)d_ws;                  // [512*512]
  u16* W2b = W1b + 512 * 512;             // [512*512]
  u16* Ab = W1b + 2 * 512 * 512;          // [2][N*D] bf16
  u16* Bb = Ab + 2 * ND;                  // [2][N*D] bf16
  float* zbf = (float*)(Bb + 2 * ND);     // 8*NN
  float* pc1 = zbf + 8 * NN;              // [128][512]
  float* pc2 = pc1 + 128 * 512;           // [128][512]
  float* t1 = pc2 + 128 * 512;            // 512
  float* t2 = t1 + 512;                   // 512
  float* hg1 = t2 + 512;                  // 512
  float* hg2 = hg1 + 512;                 // 512
  float* summ1 = hg2 + 512;               // 512
  float* summ2 = summ1 + 512;             // 512
  float* plsP = summ2 + 512;              // 64
  float* plsN = plsP + 64;                // 64
  int* ctr = (int*)(plsN + 64);           // 1 (r11 gate proved ws holds more)

  // 1) convert + colmean partials + zero zbf/ctr
  tobf16cm<<<4736, dim3(256), 0, stream>>>(lw1, lw2, z1, z2, W1b, pc1, pc2,
                                           zbf, ctr);
  // 2) layer-1 GEMM (PReLU) + mv1 (pc -> t)
  gemm_mv<1><<<576, dim3(512), 0, stream>>>(Ab, W1b, lb1, la, Bb, gw1, pc1,
                                            pc2, gb1, ga, t1, t2);
  // 3) layer-2 GEMM + mv2 (t -> hg)
  gemm_mv<0><<<576, dim3(512), 0, stream>>>(Bb, W2b, lb2, la, Ab, gw2, t1, t2,
                                            gb2, nullptr, hg1, hg2);
  // 4) row L2-normalize + mv3 (hg -> summ)
  rownorm_mv<<<2304, dim3(256), 0, stream>>>(Ab, Bb, W, hg1, hg2, summ1,
                                             summ2);
  // 5) fused similarity + logsig partials + last-block finalize -> out[0]
  sim_mfma<<<dim3(32, 34), dim3(512), 98304, stream>>>(
      Bb, Bb + ND, mask, zbf, z1, z2, summ1, summ2, plsP, plsN, ctr, out);
}